// Round 4
// baseline (283.514 us; speedup 1.0000x reference)
//
#include <hip/hip_runtime.h>
#include <hip/hip_cooperative_groups.h>

namespace cg = cooperative_groups;

#define HW 256   // h*w = 16*16
#define C  128   // channels (= d = o = p)

// Single fused cooperative kernel: 256 blocks x 1024 threads, one block/CU.
// Stage A: 512 instance-norms (x+pos, y), 2 per block.
// grid.sync()
// Stage B: per (b,o): A_j/B_i GEMV + separable z-norm stats (b1 cancels) +
//          relu-sum over j -> s[b,o,i].
// grid.sync()
// Stage C: out[b,p,i] = sum_o w2[p,o] s[b,o,i] + 256*b2[p].
__global__ __launch_bounds__(1024) void k_fused(
        const float* __restrict__ x, const float* __restrict__ y,
        const float* __restrict__ pos, const float* __restrict__ w1,
        const float* __restrict__ w2, const float* __restrict__ b2,
        float* __restrict__ xn, float* __restrict__ yn,
        float* __restrict__ sbuf, float* __restrict__ out) {
    cg::grid_group grid = cg::this_grid();

    __shared__ float pA[4][256];
    __shared__ float pB[4][256];
    __shared__ float red[16][4];
    __shared__ float aj[256];
    __shared__ float bi[256];
    __shared__ float wrow[384];

    const int t    = threadIdx.x;
    const int blk  = blockIdx.x;
    const int g    = t >> 8;     // 256-thread group 0..3
    const int l    = t & 255;    // index within group (spatial i / j)
    const int wgl  = t >> 6;     // wave 0..15
    const int lane = t & 63;

    // ---------------- Stage A: channel instance-norm + relu ----------------
    float v = 0.0f;
    float* dstA = nullptr;
    if (g < 2) {
        const int jb = blk * 2 + g;          // norm job 0..511
        if (jb < 256) {                      // x channel (b*128+c)
            const int c = jb & 127;
            v = x[jb * HW + l] + pos[l * C + c];   // pos[c][j] = pos_emb[j][c]
            dstA = xn + jb * HW;
        } else {                             // y channel
            const int bc = jb - 256;
            v = y[bc * HW + l];
            dstA = yn + bc * HW;
        }
    }
    float s1 = v, s2 = v * v;
    #pragma unroll
    for (int off = 32; off > 0; off >>= 1) {
        s1 += __shfl_xor(s1, off, 64);
        s2 += __shfl_xor(s2, off, 64);
    }
    if (lane == 0) { red[wgl][0] = s1; red[wgl][1] = s2; }
    __syncthreads();
    if (g < 2) {
        const int w0 = g * 4;                // the 4 waves of this group
        const float S1 = red[w0][0] + red[w0+1][0] + red[w0+2][0] + red[w0+3][0];
        const float S2 = red[w0][1] + red[w0+1][1] + red[w0+2][1] + red[w0+3][1];
        const float m   = S1 * (1.0f / 256.0f);
        const float var = S2 * (1.0f / 256.0f) - m * m;
        const float r   = (v - m) * rsqrtf(var + 1e-5f);
        dstA[l] = r > 0.0f ? r : 0.0f;
    }
    __threadfence();
    grid.sync();

    // ---------------- Stage B: relational core per (b,o) -------------------
    const int b = blk >> 7;
    const int o = blk & 127;
    if (t < 384) wrow[t] = w1[o * 384 + t];
    __syncthreads();

    const float* xb = xn + b * (C * HW);
    const float* yb = yn + b * (C * HW);

    float A = 0.0f, Bv = 0.0f;
    const int c0 = g * 32;                    // quarter of the channel loop
    #pragma unroll
    for (int cc = 0; cc < 32; ++cc) {
        const int c = c0 + cc;
        const float xv = xb[c * HW + l];
        A  = fmaf(wrow[c],       xv, A);
        Bv = fmaf(wrow[128 + c], xv, Bv);
        const float yv = yb[c * HW + l];
        Bv = fmaf(wrow[256 + c], yv, Bv);
    }
    pA[g][l] = A;
    pB[g][l] = Bv;
    __syncthreads();

    float Af = 0.0f, Bf = 0.0f;
    if (t < 256) {
        Af = pA[0][l] + pA[1][l] + pA[2][l] + pA[3][l];
        Bf = pB[0][l] + pB[1][l] + pB[2][l] + pB[3][l];
    }
    // block-wide moment reduction (16 waves)
    float rA = Af, rA2 = Af * Af, rB = Bf, rB2 = Bf * Bf;
    #pragma unroll
    for (int off = 32; off > 0; off >>= 1) {
        rA  += __shfl_xor(rA,  off, 64);
        rA2 += __shfl_xor(rA2, off, 64);
        rB  += __shfl_xor(rB,  off, 64);
        rB2 += __shfl_xor(rB2, off, 64);
    }
    if (lane == 0) { red[wgl][0] = rA; red[wgl][1] = rA2; red[wgl][2] = rB; red[wgl][3] = rB2; }
    __syncthreads();
    float sA = 0.f, sA2 = 0.f, sB = 0.f, sB2 = 0.f;
    #pragma unroll
    for (int w = 0; w < 16; ++w) {
        sA += red[w][0]; sA2 += red[w][1]; sB += red[w][2]; sB2 += red[w][3];
    }
    const float mA   = sA  * (1.0f / 256.0f);
    const float mB   = sB  * (1.0f / 256.0f);
    const float varA = sA2 * (1.0f / 256.0f) - mA * mA;
    const float varB = sB2 * (1.0f / 256.0f) - mB * mB;
    const float istd = rsqrtf(varA + varB + 1e-5f);

    __syncthreads();                          // red reuse barrier
    if (t < 256) {
        aj[l] = (Af - mA) * istd;             // a_j (this thread's j == l)
        bi[l] = (Bf - mB) * istd;             // b_i
    }
    __syncthreads();

    const float bb = bi[l];
    float acc = 0.0f;
    const int j0 = g * 64;                    // quarter of the j loop
    #pragma unroll
    for (int jj = 0; jj < 64; ++jj) {
        const float zv = aj[j0 + jj] + bb;    // LDS broadcast within wave
        acc += (zv > 0.0f ? zv : 0.0f);
    }
    pA[g][l] = acc;
    __syncthreads();
    if (t < 256)
        sbuf[blk * HW + l] = pA[0][l] + pA[1][l] + pA[2][l] + pA[3][l];
    __threadfence();
    grid.sync();

    // ---------------- Stage C: output GEMV ---------------------------------
    const int p = blk & 127;
    if (t < 128) wrow[t] = w2[p * 128 + t];
    __syncthreads();
    const float* sb = sbuf + b * (C * HW);
    float acc2 = 0.0f;
    const int o0 = g * 32;
    #pragma unroll
    for (int oo = 0; oo < 32; ++oo)
        acc2 = fmaf(wrow[o0 + oo], sb[(o0 + oo) * HW + l], acc2);
    pB[g][l] = acc2;
    __syncthreads();
    if (t < 256)
        out[blk * HW + l] = pB[0][l] + pB[1][l] + pB[2][l] + pB[3][l]
                            + 256.0f * b2[p];
}

extern "C" void kernel_launch(void* const* d_in, const int* in_sizes, int n_in,
                              void* d_out, int out_size, void* d_ws, size_t ws_size,
                              hipStream_t stream) {
    const float* x   = (const float*)d_in[0];   // (2,128,16,16)
    const float* y   = (const float*)d_in[1];   // (2,128,16,16)
    const float* pos = (const float*)d_in[2];   // (256,128)
    const float* w1  = (const float*)d_in[3];   // (128,384)
    // d_in[4] = b1: cancelled by the z instance-norm -> unused.
    const float* w2  = (const float*)d_in[5];   // (128,128)
    const float* b2  = (const float*)d_in[6];   // (128,)
    float* out = (float*)d_out;                 // (2,128,16,16) flat = 65536

    float* xn = (float*)d_ws;        // 65536 f32
    float* yn = xn + 65536;          // 65536 f32
    float* sb = yn + 65536;          // 65536 f32

    void* args[] = { (void*)&x, (void*)&y, (void*)&pos, (void*)&w1,
                     (void*)&w2, (void*)&b2,
                     (void*)&xn, (void*)&yn, (void*)&sb, (void*)&out };
    hipLaunchCooperativeKernel((const void*)k_fused, dim3(256), dim3(1024),
                               args, 0, stream);
}

// Round 5
// 85.150 us; speedup vs baseline: 3.3296x; 3.3296x over previous
//
#include <hip/hip_runtime.h>

#define HW 256   // h*w = 16*16
#define C  128   // channels (= d = o = p)

// ---- Kernel 1: fused instance-norm + relational core -------------------
// grid = 256 blocks (b*128+o), 1024 threads (16 waves).
// Each block recomputes the 256 channel-norms of its batch inline
// (redundant across the 128 blocks of a batch; compute is free here):
//   wave w handles x-channels c=8w..8w+7 and y-channels d=8w..8w+7,
//   each lane owns 4 spatial positions (float4), norm via wave shfl-reduce,
//   normalized relu values FMA'd straight into A/B partials (never stored).
// Then the separable z-norm (b1 cancels; mean=Ā+B̄, var=var(A)+var(B)),
// relu-sum over j -> s[b,o,i].
__global__ __launch_bounds__(1024) void k_rel(
        const float* __restrict__ x, const float* __restrict__ y,
        const float* __restrict__ pos, const float* __restrict__ w1,
        float* __restrict__ s_out) {
    __shared__ float pA[16][256];
    __shared__ float pB[16][256];
    __shared__ float red[16][4];
    __shared__ float aj[256];
    __shared__ float bi[256];
    __shared__ float wrow[384];

    const int t    = threadIdx.x;
    const int l    = t & 255;    // spatial index within group (i / j)
    const int g    = t >> 8;     // 256-thread group 0..3
    const int w    = t >> 6;     // wave 0..15
    const int lane = t & 63;
    const int bo   = blockIdx.x;
    const int b    = bo >> 7;
    const int o    = bo & 127;

    if (t < 384) wrow[t] = w1[o * 384 + t];
    __syncthreads();

    const float* xb = x + b * (C * HW);
    const float* yb = y + b * (C * HW);
    const int j4 = lane * 4;     // this lane's 4 spatial positions

    float A4[4]  = {0.f, 0.f, 0.f, 0.f};
    float B4[4]  = {0.f, 0.f, 0.f, 0.f};

    #pragma unroll
    for (int r = 0; r < 8; ++r) {
        const int c = w * 8 + r;                 // x-channel for this wave
        const float4 xv = *reinterpret_cast<const float4*>(xb + c * HW + j4);
        float v[4] = { xv.x + pos[(j4 + 0) * C + c],
                       xv.y + pos[(j4 + 1) * C + c],
                       xv.z + pos[(j4 + 2) * C + c],
                       xv.w + pos[(j4 + 3) * C + c] };
        float s1 = v[0] + v[1] + v[2] + v[3];
        float s2 = v[0]*v[0] + v[1]*v[1] + v[2]*v[2] + v[3]*v[3];
        #pragma unroll
        for (int off = 32; off > 0; off >>= 1) {
            s1 += __shfl_xor(s1, off, 64);
            s2 += __shfl_xor(s2, off, 64);
        }
        const float m    = s1 * (1.0f / 256.0f);
        const float var  = s2 * (1.0f / 256.0f) - m * m;
        const float istd = rsqrtf(var + 1e-5f);
        const float wi = wrow[c], wj = wrow[128 + c];
        #pragma unroll
        for (int k = 0; k < 4; ++k) {
            float nv = (v[k] - m) * istd;
            nv = nv > 0.f ? nv : 0.f;
            A4[k] = fmaf(wi, nv, A4[k]);
            B4[k] = fmaf(wj, nv, B4[k]);
        }
    }
    #pragma unroll
    for (int r = 0; r < 8; ++r) {
        const int d = w * 8 + r;                 // y-channel for this wave
        const float4 yv = *reinterpret_cast<const float4*>(yb + d * HW + j4);
        float v[4] = { yv.x, yv.y, yv.z, yv.w };
        float s1 = v[0] + v[1] + v[2] + v[3];
        float s2 = v[0]*v[0] + v[1]*v[1] + v[2]*v[2] + v[3]*v[3];
        #pragma unroll
        for (int off = 32; off > 0; off >>= 1) {
            s1 += __shfl_xor(s1, off, 64);
            s2 += __shfl_xor(s2, off, 64);
        }
        const float m    = s1 * (1.0f / 256.0f);
        const float var  = s2 * (1.0f / 256.0f) - m * m;
        const float istd = rsqrtf(var + 1e-5f);
        const float wy = wrow[256 + d];
        #pragma unroll
        for (int k = 0; k < 4; ++k) {
            float nv = (v[k] - m) * istd;
            nv = nv > 0.f ? nv : 0.f;
            B4[k] = fmaf(wy, nv, B4[k]);
        }
    }

    // deposit per-wave partials: wave w covered channels 8w..8w+7
    #pragma unroll
    for (int k = 0; k < 4; ++k) {
        pA[w][j4 + k] = A4[k];
        pB[w][j4 + k] = B4[k];
    }
    __syncthreads();

    // combine the 16 wave-partials (t<256 owns i=t)
    float Af = 0.f, Bf = 0.f;
    if (t < 256) {
        #pragma unroll
        for (int ww = 0; ww < 16; ++ww) { Af += pA[ww][l]; Bf += pB[ww][l]; }
    }

    // block-wide moment reduction (threads >=256 contribute zeros)
    float rA = Af, rA2 = Af * Af, rB = Bf, rB2 = Bf * Bf;
    #pragma unroll
    for (int off = 32; off > 0; off >>= 1) {
        rA  += __shfl_xor(rA,  off, 64);
        rA2 += __shfl_xor(rA2, off, 64);
        rB  += __shfl_xor(rB,  off, 64);
        rB2 += __shfl_xor(rB2, off, 64);
    }
    if (lane == 0) { red[w][0] = rA; red[w][1] = rA2; red[w][2] = rB; red[w][3] = rB2; }
    __syncthreads();
    float sA = 0.f, sA2 = 0.f, sB = 0.f, sB2 = 0.f;
    #pragma unroll
    for (int ww = 0; ww < 16; ++ww) {
        sA += red[ww][0]; sA2 += red[ww][1]; sB += red[ww][2]; sB2 += red[ww][3];
    }
    const float mA   = sA  * (1.0f / 256.0f);
    const float mB   = sB  * (1.0f / 256.0f);
    const float varA = sA2 * (1.0f / 256.0f) - mA * mA;
    const float varB = sB2 * (1.0f / 256.0f) - mB * mB;
    const float istd = rsqrtf(varA + varB + 1e-5f);

    if (t < 256) {
        aj[l] = (Af - mA) * istd;   // a_j (this thread's j == l)
        bi[l] = (Bf - mB) * istd;   // b_i
    }
    __syncthreads();

    // quarter of the relu-sum over j
    const float bb = bi[l];
    float acc = 0.f;
    const int j0 = g * 64;
    #pragma unroll
    for (int jj = 0; jj < 64; ++jj) {
        const float zv = aj[j0 + jj] + bb;     // LDS broadcast within wave
        acc += (zv > 0.f ? zv : 0.f);
    }
    pA[g][l] = acc;
    __syncthreads();
    if (t < 256)
        s_out[bo * HW + l] = pA[0][l] + pA[1][l] + pA[2][l] + pA[3][l];
}

// ---- Kernel 2: out[b,p,i] = Σ_o w2[p,o]·s[b,o,i] + 256·b2[p] -----------
// grid = 256 (b*128+p), 1024 threads, quarter-split over o.
__global__ __launch_bounds__(1024) void k_out(
        const float* __restrict__ s_in, const float* __restrict__ w2,
        const float* __restrict__ b2, float* __restrict__ out) {
    __shared__ float wrow[128];
    __shared__ float pacc[4][256];
    const int t  = threadIdx.x;
    const int l  = t & 255;
    const int g  = t >> 8;
    const int bp = blockIdx.x;
    const int b  = bp >> 7;
    const int p  = bp & 127;
    if (t < 128) wrow[t] = w2[p * 128 + t];
    __syncthreads();
    const float* sb = s_in + b * (C * HW);
    float acc = 0.f;
    const int o0 = g * 32;
    #pragma unroll
    for (int oo = 0; oo < 32; ++oo)
        acc = fmaf(wrow[o0 + oo], sb[(o0 + oo) * HW + l], acc);
    pacc[g][l] = acc;
    __syncthreads();
    if (t < 256)
        out[bp * HW + l] = pacc[0][l] + pacc[1][l] + pacc[2][l] + pacc[3][l]
                           + 256.0f * b2[p];
}

extern "C" void kernel_launch(void* const* d_in, const int* in_sizes, int n_in,
                              void* d_out, int out_size, void* d_ws, size_t ws_size,
                              hipStream_t stream) {
    const float* x   = (const float*)d_in[0];   // (2,128,16,16)
    const float* y   = (const float*)d_in[1];   // (2,128,16,16)
    const float* pos = (const float*)d_in[2];   // (256,128)
    const float* w1  = (const float*)d_in[3];   // (128,384)
    // d_in[4] = b1: cancelled by the z instance-norm -> unused.
    const float* w2  = (const float*)d_in[5];   // (128,128)
    const float* b2  = (const float*)d_in[6];   // (128,)
    float* out = (float*)d_out;                 // (2,128,16,16) flat = 65536

    float* s = (float*)d_ws;         // 65536 f32 intermediate

    k_rel<<<256, 1024, 0, stream>>>(x, y, pos, w1, s);
    k_out<<<256, 1024, 0, stream>>>(s, w2, b2, out);
}

// Round 14
// 77.179 us; speedup vs baseline: 3.6735x; 1.1033x over previous
//
#include <hip/hip_runtime.h>

#define HW 256   // h*w = 16*16
#define C  128   // channels (= d = o = p)

__device__ __forceinline__ float relu(float v) { return v > 0.f ? v : 0.f; }

// ---- Kernel 1: instance-norm + relu, one wave per channel ---------------
// grid = 512 x 64 threads. blk<256 -> x channel (b*128+c), else y channel.
// Lane owns 4 spatial positions (float4); stats via pure shfl reduce.
__global__ __launch_bounds__(64) void k_norm(
        const float* __restrict__ x, const float* __restrict__ y,
        const float* __restrict__ pos, float* __restrict__ xn, float* __restrict__ yn) {
    const int blk  = blockIdx.x;
    const int lane = threadIdx.x;
    const int j4   = lane * 4;

    float v0, v1, v2, v3;
    float* dst;
    if (blk < 256) {
        const int c = blk & 127;
        const float4 xv = *reinterpret_cast<const float4*>(x + blk * HW + j4);
        v0 = xv.x + pos[(j4 + 0) * C + c];
        v1 = xv.y + pos[(j4 + 1) * C + c];
        v2 = xv.z + pos[(j4 + 2) * C + c];
        v3 = xv.w + pos[(j4 + 3) * C + c];
        dst = xn + blk * HW;
    } else {
        const int bc = blk - 256;
        const float4 yv = *reinterpret_cast<const float4*>(y + bc * HW + j4);
        v0 = yv.x; v1 = yv.y; v2 = yv.z; v3 = yv.w;
        dst = yn + bc * HW;
    }
    float s1 = v0 + v1 + v2 + v3;
    float s2 = v0*v0 + v1*v1 + v2*v2 + v3*v3;
    #pragma unroll
    for (int off = 32; off > 0; off >>= 1) {
        s1 += __shfl_xor(s1, off, 64);
        s2 += __shfl_xor(s2, off, 64);
    }
    const float m    = s1 * (1.0f / 256.0f);
    const float var  = s2 * (1.0f / 256.0f) - m * m;
    const float istd = rsqrtf(var + 1e-5f);
    float4 r;
    r.x = relu((v0 - m) * istd);
    r.y = relu((v1 - m) * istd);
    r.z = relu((v2 - m) * istd);
    r.w = relu((v3 - m) * istd);
    *reinterpret_cast<float4*>(dst + j4) = r;
}

// ---- Kernel 2: relational core per (b,o) --------------------------------
// z[b,o,i,j] = A[j] + B[i] + b1[o]; b1 cancels under the instance norm;
// mean(z)=Ā+B̄, var(z)=var(A)+var(B). s[b,o,i] = Σ_j relu(a_j + b_i).
// grid = 256 (b*128+o) x 1024 threads (16 waves).
// GEMV: wave w owns channels 8w..8w+7 of both xn and yn; lane owns 4 j's
// (float4 loads); per-wave partials in LDS. Weights w1 are read directly
// from global (wave-uniform address -> scalar loads).
__global__ __launch_bounds__(1024) void k_rel(
        const float* __restrict__ xn, const float* __restrict__ yn,
        const float* __restrict__ w1, float* __restrict__ s_out) {
    __shared__ float pA[16][256];
    __shared__ float pB[16][256];
    __shared__ float red[16][4];
    __shared__ __align__(16) float aj[256];
    __shared__ float bi[256];

    const int t    = threadIdx.x;
    const int l    = t & 255;    // spatial index (i / j)
    const int g    = t >> 8;     // quarter 0..3
    const int w    = t >> 6;     // wave 0..15
    const int lane = t & 63;
    const int j4   = lane * 4;
    const int bo   = blockIdx.x;
    const int b    = bo >> 7;
    const int o    = bo & 127;

    const float* xb = xn + b * (C * HW);
    const float* yb = yn + b * (C * HW);
    const float* wr = w1 + o * 384;

    float A4[4] = {0.f, 0.f, 0.f, 0.f};
    float B4[4] = {0.f, 0.f, 0.f, 0.f};
    #pragma unroll
    for (int r = 0; r < 8; ++r) {
        const int c = w * 8 + r;
        const float wi = wr[c], wj = wr[128 + c], wy = wr[256 + c];
        const float4 xv = *reinterpret_cast<const float4*>(xb + c * HW + j4);
        const float4 yv = *reinterpret_cast<const float4*>(yb + c * HW + j4);
        A4[0] = fmaf(wi, xv.x, A4[0]);  B4[0] = fmaf(wj, xv.x, fmaf(wy, yv.x, B4[0]));
        A4[1] = fmaf(wi, xv.y, A4[1]);  B4[1] = fmaf(wj, xv.y, fmaf(wy, yv.y, B4[1]));
        A4[2] = fmaf(wi, xv.z, A4[2]);  B4[2] = fmaf(wj, xv.z, fmaf(wy, yv.z, B4[2]));
        A4[3] = fmaf(wi, xv.w, A4[3]);  B4[3] = fmaf(wj, xv.w, fmaf(wy, yv.w, B4[3]));
    }
    #pragma unroll
    for (int k = 0; k < 4; ++k) {
        pA[w][j4 + k] = A4[k];
        pB[w][j4 + k] = B4[k];
    }
    __syncthreads();

    // combine the 16 wave-partials (t<256 owns position l)
    float Af = 0.f, Bf = 0.f;
    if (t < 256) {
        #pragma unroll
        for (int ww = 0; ww < 16; ++ww) { Af += pA[ww][l]; Bf += pB[ww][l]; }
    }

    // block-wide moment reduction (threads >=256 contribute zeros)
    float rA = Af, rA2 = Af * Af, rB = Bf, rB2 = Bf * Bf;
    #pragma unroll
    for (int off = 32; off > 0; off >>= 1) {
        rA  += __shfl_xor(rA,  off, 64);
        rA2 += __shfl_xor(rA2, off, 64);
        rB  += __shfl_xor(rB,  off, 64);
        rB2 += __shfl_xor(rB2, off, 64);
    }
    if (lane == 0) { red[w][0] = rA; red[w][1] = rA2; red[w][2] = rB; red[w][3] = rB2; }
    __syncthreads();
    float sA = 0.f, sA2 = 0.f, sB = 0.f, sB2 = 0.f;
    #pragma unroll
    for (int ww = 0; ww < 16; ++ww) {
        sA += red[ww][0]; sA2 += red[ww][1]; sB += red[ww][2]; sB2 += red[ww][3];
    }
    const float mA   = sA  * (1.0f / 256.0f);
    const float mB   = sB  * (1.0f / 256.0f);
    const float varA = sA2 * (1.0f / 256.0f) - mA * mA;
    const float varB = sB2 * (1.0f / 256.0f) - mB * mB;
    const float istd = rsqrtf(varA + varB + 1e-5f);

    if (t < 256) {
        aj[l] = (Af - mA) * istd;   // a_j (this thread's j == l)
        bi[l] = (Bf - mB) * istd;   // b_i
    }
    __syncthreads();

    // quarter of the relu-sum over j, aj read as float4 (ds_read_b128)
    const float bb = bi[l];
    const float4* aj4 = reinterpret_cast<const float4*>(aj);
    float acc = 0.f;
    #pragma unroll
    for (int jj = 0; jj < 16; ++jj) {
        const float4 a = aj4[g * 16 + jj];   // broadcast within wave
        acc += relu(a.x + bb) + relu(a.y + bb) + relu(a.z + bb) + relu(a.w + bb);
    }
    pA[g][l] = acc;
    __syncthreads();
    if (t < 256)
        s_out[bo * HW + l] = pA[0][l] + pA[1][l] + pA[2][l] + pA[3][l];
}

// ---- Kernel 3: out[b,p,i] = Σ_o w2[p,o]·s[b,o,i] + 256·b2[p] ------------
// grid = 256 (b*128+p) x 1024 threads; wave w owns o-channels 8w..8w+7,
// lane owns 4 i's (float4).
__global__ __launch_bounds__(1024) void k_out(
        const float* __restrict__ s_in, const float* __restrict__ w2,
        const float* __restrict__ b2, float* __restrict__ out) {
    __shared__ float pacc[16][256];
    const int t    = threadIdx.x;
    const int l    = t & 255;
    const int w    = t >> 6;
    const int lane = t & 63;
    const int j4   = lane * 4;
    const int bp   = blockIdx.x;
    const int b    = bp >> 7;
    const int p    = bp & 127;

    const float* sb = s_in + b * (C * HW);
    const float* wr = w2 + p * 128;
    float a0 = 0.f, a1 = 0.f, a2 = 0.f, a3 = 0.f;
    #pragma unroll
    for (int r = 0; r < 8; ++r) {
        const int o = w * 8 + r;
        const float wv = wr[o];
        const float4 sv = *reinterpret_cast<const float4*>(sb + o * HW + j4);
        a0 = fmaf(wv, sv.x, a0);
        a1 = fmaf(wv, sv.y, a1);
        a2 = fmaf(wv, sv.z, a2);
        a3 = fmaf(wv, sv.w, a3);
    }
    pacc[w][j4 + 0] = a0;
    pacc[w][j4 + 1] = a1;
    pacc[w][j4 + 2] = a2;
    pacc[w][j4 + 3] = a3;
    __syncthreads();
    if (t < 256) {
        float acc = 256.0f * b2[p];
        #pragma unroll
        for (int ww = 0; ww < 16; ++ww) acc += pacc[ww][l];
        out[bp * HW + l] = acc;
    }
}

extern "C" void kernel_launch(void* const* d_in, const int* in_sizes, int n_in,
                              void* d_out, int out_size, void* d_ws, size_t ws_size,
                              hipStream_t stream) {
    const float* x   = (const float*)d_in[0];   // (2,128,16,16)
    const float* y   = (const float*)d_in[1];   // (2,128,16,16)
    const float* pos = (const float*)d_in[2];   // (256,128)
    const float* w1  = (const float*)d_in[3];   // (128,384)
    // d_in[4] = b1: cancelled by the z instance-norm -> unused.
    const float* w2  = (const float*)d_in[5];   // (128,128)
    const float* b2  = (const float*)d_in[6];   // (128,)
    float* out = (float*)d_out;                 // (2,128,16,16) flat = 65536

    float* xn = (float*)d_ws;        // 65536 f32
    float* yn = xn + 65536;          // 65536 f32
    float* s  = yn + 65536;          // 65536 f32

    k_norm<<<512,  64, 0, stream>>>(x, y, pos, xn, yn);
    k_rel <<<256, 1024, 0, stream>>>(xn, yn, w1, s);
    k_out <<<256, 1024, 0, stream>>>(s, w2, b2, out);
}